// Round 1
// baseline (188.400 us; speedup 1.0000x reference)
//
#include <hip/hip_runtime.h>

// CoAttention: L1=L2=512, B=2, D1=D2=256, BN=256, all fp32.
// Pipeline:
//  k_proj    : q1[b,l,k]=(ctx1@Wh1+bh)*2log2e ; q2[b,m,k]=(ctx2@Wh2)*2log2e ; SW=sum(wo)
//  k_aff     : aff[b,l,m] = SW + sum_k (-2*wo_k) / (exp2(q1+q2)+1)  (+mask penalties)
//              writes aff and its transpose afft via LDS-staged transpose
//  k_softmax : row softmax of aff  -> d12t[b,m,l]   (transposed write)
//              row softmax of afft -> d21 [b,l,m]   (transposed write)
//  k_ctx     : C12[m,b,:] = d12t[b,m,:] @ ctx1[:,b,:] ; C21[l,b,:] = d21[b,l,:] @ ctx2[:,b,:]
//  k_out     : out = tanh(concat(ctx,C) @ W + bias), both directions

#define NEGC (-1e12f)
#define TWO_LOG2E 2.8853900817779268f
#define LOG2E 1.4426950408889634f

__global__ __launch_bounds__(256) void k_proj(
    const float* __restrict__ ctx1, const float* __restrict__ ctx2,
    const float* __restrict__ Wh, const float* __restrict__ bh,
    const float* __restrict__ wo,
    float* __restrict__ q1, float* __restrict__ q2, float* __restrict__ SW)
{
    const int t  = threadIdx.x;
    const int bx = blockIdx.x;
    const bool is2 = (bx >= 128);
    const int rb = (bx & 127) * 8;              // 8 output rows per block, rows = b*512+l
    const float* __restrict__ ctx = is2 ? ctx2 : ctx1;
    const float* __restrict__ W   = Wh + (is2 ? 256 * 256 : 0);
    float* __restrict__ qout      = is2 ? q2 : q1;

    __shared__ __align__(16) float xs[8 * 256];
    __shared__ float red[256];

    #pragma unroll
    for (int i = 0; i < 8; ++i) {
        int row = rb + i;
        int l = row & 511, b = row >> 9;
        xs[i * 256 + t] = ctx[(l * 2 + b) * 256 + t];
    }
    if (bx == 0) red[t] = wo[t];
    __syncthreads();
    if (bx == 0) {                               // block-uniform branch: barriers legal
        for (int s = 128; s > 0; s >>= 1) {
            if (t < s) red[t] += red[t + s];
            __syncthreads();
        }
        if (t == 0) SW[0] = red[0];
    }

    float acc[8] = {0.f, 0.f, 0.f, 0.f, 0.f, 0.f, 0.f, 0.f};
    for (int d0 = 0; d0 < 256; d0 += 4) {
        float w0 = W[(d0 + 0) * 256 + t];
        float w1 = W[(d0 + 1) * 256 + t];
        float w2 = W[(d0 + 2) * 256 + t];
        float w3 = W[(d0 + 3) * 256 + t];
        #pragma unroll
        for (int i = 0; i < 8; ++i) {
            const float4 x = *(const float4*)(xs + i * 256 + d0);   // LDS broadcast
            acc[i] += x.x * w0 + x.y * w1 + x.z * w2 + x.w * w3;
        }
    }
    const float bias = is2 ? 0.f : bh[t];
    #pragma unroll
    for (int i = 0; i < 8; ++i)
        qout[(rb + i) * 256 + t] = (acc[i] + bias) * TWO_LOG2E;
}

__global__ __launch_bounds__(256) void k_aff(
    const float* __restrict__ q1g, const float* __restrict__ q2g,
    const float* __restrict__ wo, const float* __restrict__ SWp,
    const float* __restrict__ mask1, const float* __restrict__ mask2,
    float* __restrict__ aff, float* __restrict__ afft)
{
    const int t  = threadIdx.x;
    const int l0 = blockIdx.x * 32, m0 = blockIdx.y * 32, b = blockIdx.z;

    // stride 132: bank = (4*row + k) % 32 -> 8 distinct banks across the 8
    // broadcast groups of a wave; conflict-free reads.
    __shared__ __align__(16) float q1s[32 * 132];
    __shared__ __align__(16) float q2s[32 * 132];
    __shared__ __align__(16) float wos[256];
    __shared__ float affs[32 * 33];

    wos[t] = -2.f * wo[t];

    const int l = t >> 3, mi = t & 7;            // thread: 1 l  x  4 m's (mi+8j)
    float acc[4] = {0.f, 0.f, 0.f, 0.f};

    for (int kc = 0; kc < 256; kc += 128) {
        #pragma unroll
        for (int i = 0; i < 4; ++i) {
            int idx = i * 256 + t;
            int row = idx >> 5;
            int c4  = (idx & 31) << 2;
            *(float4*)(q1s + row * 132 + c4) =
                *(const float4*)(q1g + (((b << 9) + l0 + row) << 8) + kc + c4);
            *(float4*)(q2s + row * 132 + c4) =
                *(const float4*)(q2g + (((b << 9) + m0 + row) << 8) + kc + c4);
        }
        __syncthreads();
        for (int k0 = 0; k0 < 128; k0 += 4) {
            const float4 a = *(const float4*)(q1s + l * 132 + k0);
            const float4 w = *(const float4*)(wos + kc + k0);
            #pragma unroll
            for (int j = 0; j < 4; ++j) {
                const float4 q = *(const float4*)(q2s + (mi + (j << 3)) * 132 + k0);
                float r0 = __builtin_amdgcn_rcpf(__builtin_amdgcn_exp2f(a.x + q.x) + 1.f);
                float r1 = __builtin_amdgcn_rcpf(__builtin_amdgcn_exp2f(a.y + q.y) + 1.f);
                float r2 = __builtin_amdgcn_rcpf(__builtin_amdgcn_exp2f(a.z + q.z) + 1.f);
                float r3 = __builtin_amdgcn_rcpf(__builtin_amdgcn_exp2f(a.w + q.w) + 1.f);
                acc[j] += w.x * r0 + w.y * r1 + w.z * r2 + w.w * r3;
            }
        }
        __syncthreads();
    }

    const float sw   = SWp[0];
    const float pen1 = (1.f - mask1[(l0 + l) * 2 + b]) * NEGC;
    #pragma unroll
    for (int j = 0; j < 4; ++j) {
        int m = mi + (j << 3);
        affs[l * 33 + m] = sw + acc[j] + pen1 + (1.f - mask2[(m0 + m) * 2 + b]) * NEGC;
    }
    __syncthreads();
    #pragma unroll
    for (int i = 0; i < 4; ++i) {
        int idx = i * 256 + t;
        int r = idx >> 5, c = idx & 31;
        aff [((b << 9) + l0 + r) * 512 + m0 + c] = affs[r * 33 + c];
        afft[((b << 9) + m0 + r) * 512 + l0 + c] = affs[c * 33 + r];
    }
}

__global__ __launch_bounds__(256) void k_softmax(
    const float* __restrict__ aff, const float* __restrict__ afft,
    float* __restrict__ d12t, float* __restrict__ d21)
{
    const int t = threadIdx.x;
    const int r = blockIdx.x;                    // 0..2047
    const bool second = (r >= 1024);
    const int rr = r & 1023;
    const float* __restrict__ src = (second ? afft : aff) + rr * 512;
    float* __restrict__ dst = second ? d21 : d12t;
    const int b = rr >> 9, x = rr & 511;

    __shared__ float red[256];
    float v0 = src[t], v1 = src[t + 256];
    red[t] = fmaxf(v0, v1);
    __syncthreads();
    for (int s = 128; s > 0; s >>= 1) {
        if (t < s) red[t] = fmaxf(red[t], red[t + s]);
        __syncthreads();
    }
    const float mx = red[0];
    __syncthreads();
    float e0 = __builtin_amdgcn_exp2f((v0 - mx) * LOG2E);
    float e1 = __builtin_amdgcn_exp2f((v1 - mx) * LOG2E);
    red[t] = e0 + e1;
    __syncthreads();
    for (int s = 128; s > 0; s >>= 1) {
        if (t < s) red[t] += red[t + s];
        __syncthreads();
    }
    const float inv = __builtin_amdgcn_rcpf(red[0]);
    dst[((b << 9) + t) * 512 + x]       = e0 * inv;   // transposed write
    dst[((b << 9) + t + 256) * 512 + x] = e1 * inv;
}

// generic 64x32-tile f32 GEMM bodies ------------------------------------

__global__ __launch_bounds__(256) void k_ctx(
    const float* __restrict__ d12t, const float* __restrict__ d21,
    const float* __restrict__ ctx1, const float* __restrict__ ctx2,
    float* __restrict__ C12, float* __restrict__ C21)
{
    const int t = threadIdx.x;
    const int m0 = blockIdx.x * 64, n0 = blockIdx.y * 32;
    const int dir = blockIdx.z >> 1, b = blockIdx.z & 1;
    const float* __restrict__ D = (dir == 0 ? d12t : d21) + b * (512 * 512); // 512-stride
    const float* __restrict__ X = (dir == 0 ? ctx1 : ctx2) + b * 256;        // 512-stride
    float*       __restrict__ C = (dir == 0 ? C12 : C21) + b * 256;          // 512-stride

    __shared__ __align__(16) float As[16 * 68];   // A^T tile: [k][m]
    __shared__ __align__(16) float Bs[16 * 34];   // B tile:   [k][n]
    const int tm = t >> 4, tn = t & 15;
    const int m4 = tm << 2, n2 = tn << 1;
    float a00=0,a01=0,a10=0,a11=0,a20=0,a21=0,a30=0,a31=0;

    for (int k0 = 0; k0 < 512; k0 += 16) {
        #pragma unroll
        for (int i = 0; i < 4; ++i) {
            int idx = i * 256 + t, am = idx >> 4, ak = idx & 15;
            As[ak * 68 + am] = D[(m0 + am) * 512 + k0 + ak];
        }
        #pragma unroll
        for (int i = 0; i < 2; ++i) {
            int idx = i * 256 + t, bk = idx >> 5, bn = idx & 31;
            Bs[bk * 34 + bn] = X[(k0 + bk) * 512 + n0 + bn];
        }
        __syncthreads();
        #pragma unroll
        for (int kk = 0; kk < 16; ++kk) {
            const float4 a  = *(const float4*)(As + kk * 68 + m4);
            const float2 bv = *(const float2*)(Bs + kk * 34 + n2);
            a00 += a.x * bv.x; a01 += a.x * bv.y;
            a10 += a.y * bv.x; a11 += a.y * bv.y;
            a20 += a.z * bv.x; a21 += a.z * bv.y;
            a30 += a.w * bv.x; a31 += a.w * bv.y;
        }
        __syncthreads();
    }
    const int c0 = n0 + n2;
    C[(m0 + m4 + 0) * 512 + c0] = a00; C[(m0 + m4 + 0) * 512 + c0 + 1] = a01;
    C[(m0 + m4 + 1) * 512 + c0] = a10; C[(m0 + m4 + 1) * 512 + c0 + 1] = a11;
    C[(m0 + m4 + 2) * 512 + c0] = a20; C[(m0 + m4 + 2) * 512 + c0 + 1] = a21;
    C[(m0 + m4 + 3) * 512 + c0] = a30; C[(m0 + m4 + 3) * 512 + c0 + 1] = a31;
}

__global__ __launch_bounds__(256) void k_out(
    const float* __restrict__ ctx1, const float* __restrict__ ctx2,
    const float* __restrict__ C12, const float* __restrict__ C21,
    const float* __restrict__ W12, const float* __restrict__ b12,
    const float* __restrict__ W21, const float* __restrict__ b21,
    float* __restrict__ out)
{
    const int t = threadIdx.x;
    const int m0 = blockIdx.x * 64, n0 = blockIdx.y * 32;
    const int dir = blockIdx.z >> 1, b = blockIdx.z & 1;
    const float* __restrict__ A1   = (dir == 0 ? ctx2 : ctx1) + b * 256;  // 512-stride
    const float* __restrict__ A2   = (dir == 0 ? C12 : C21) + b * 256;    // 512-stride
    const float* __restrict__ W    = (dir == 0 ? W12 : W21);              // 256-stride
    const float* __restrict__ bias = (dir == 0 ? b12 : b21);
    float* __restrict__ o = out + (dir == 0 ? 512 * 2 * 256 : 0) + b * 256;

    __shared__ __align__(16) float As[16 * 68];
    __shared__ __align__(16) float Bs[16 * 34];
    const int tm = t >> 4, tn = t & 15;
    const int m4 = tm << 2, n2 = tn << 1;
    float a00=0,a01=0,a10=0,a11=0,a20=0,a21=0,a30=0,a31=0;

    for (int k0 = 0; k0 < 512; k0 += 16) {
        const float* __restrict__ Ab = (k0 < 256) ? (A1 + k0) : (A2 + (k0 - 256));
        #pragma unroll
        for (int i = 0; i < 4; ++i) {
            int idx = i * 256 + t, am = idx >> 4, ak = idx & 15;
            As[ak * 68 + am] = Ab[(m0 + am) * 512 + ak];
        }
        #pragma unroll
        for (int i = 0; i < 2; ++i) {
            int idx = i * 256 + t, bk = idx >> 5, bn = idx & 31;
            Bs[bk * 34 + bn] = W[(k0 + bk) * 256 + n0 + bn];
        }
        __syncthreads();
        #pragma unroll
        for (int kk = 0; kk < 16; ++kk) {
            const float4 a  = *(const float4*)(As + kk * 68 + m4);
            const float2 bv = *(const float2*)(Bs + kk * 34 + n2);
            a00 += a.x * bv.x; a01 += a.x * bv.y;
            a10 += a.y * bv.x; a11 += a.y * bv.y;
            a20 += a.z * bv.x; a21 += a.z * bv.y;
            a30 += a.w * bv.x; a31 += a.w * bv.y;
        }
        __syncthreads();
    }
    float accs[4][2] = {{a00,a01},{a10,a11},{a20,a21},{a30,a31}};
    #pragma unroll
    for (int i = 0; i < 4; ++i) {
        #pragma unroll
        for (int j = 0; j < 2; ++j) {
            const int col = n0 + n2 + j;
            const float v = accs[i][j] + bias[col];
            const float e = __builtin_amdgcn_exp2f(v * TWO_LOG2E);
            o[(m0 + m4 + i) * 512 + col] = 1.f - 2.f * __builtin_amdgcn_rcpf(e + 1.f);
        }
    }
}

extern "C" void kernel_launch(void* const* d_in, const int* in_sizes, int n_in,
                              void* d_out, int out_size, void* d_ws, size_t ws_size,
                              hipStream_t stream)
{
    const float* ctx1 = (const float*)d_in[0];
    const float* ctx2 = (const float*)d_in[1];
    const float* m1   = (const float*)d_in[2];
    const float* m2   = (const float*)d_in[3];
    const float* Wh   = (const float*)d_in[4];
    const float* bh   = (const float*)d_in[5];
    const float* wo   = (const float*)d_in[6];
    const float* W12  = (const float*)d_in[7];
    const float* b12  = (const float*)d_in[8];
    const float* W21  = (const float*)d_in[9];
    const float* b21  = (const float*)d_in[10];
    float* out = (float*)d_out;
    float* ws  = (float*)d_ws;

    float* q1   = ws;                 // 262144
    float* q2   = q1 + 262144;        // 262144
    float* SW   = q2 + 262144;        // 256 (1 used)
    float* aff  = SW + 256;           // 524288
    float* afft = aff + 524288;       // 524288
    float* d12t = afft + 524288;      // 524288
    float* d21  = d12t + 524288;      // 524288
    float* C12  = d21 + 524288;       // 262144
    float* C21  = C12 + 262144;       // 262144  (total ~12.6 MB)

    hipLaunchKernelGGL(k_proj, dim3(256), dim3(256), 0, stream,
                       ctx1, ctx2, Wh, bh, wo, q1, q2, SW);
    hipLaunchKernelGGL(k_aff, dim3(16, 16, 2), dim3(256), 0, stream,
                       q1, q2, wo, SW, m1, m2, aff, afft);
    hipLaunchKernelGGL(k_softmax, dim3(2048), dim3(256), 0, stream,
                       aff, afft, d12t, d21);
    hipLaunchKernelGGL(k_ctx, dim3(8, 8, 4), dim3(256), 0, stream,
                       d12t, d21, ctx1, ctx2, C12, C21);
    hipLaunchKernelGGL(k_out, dim3(8, 8, 4), dim3(256), 0, stream,
                       ctx1, ctx2, C12, C21, W12, b12, W21, b21, out);
}

// Round 2
// 151.360 us; speedup vs baseline: 1.2447x; 1.2447x over previous
//
#include <hip/hip_runtime.h>

// CoAttention: L1=L2=512, B=2, D1=D2=256, BN=256, fp32.
// Round 2 restructure:
//  k_proj : 6 batched GEMMs (1024x256 @ 256x256):
//           E1=exp2((ctx1@Wh1+bh)*2log2e), E2=exp2(ctx2@Wh2*2log2e),
//           P12=ctx2@W12a+b12, U1=ctx1@W12b, P21=ctx1@W21a+b21, U2=ctx2@W21b
//           (+ penalty arrays). Reassociation: C12@W12b == dist12^T @ U1.
//  k_aff  : partial_s[b,l,m] = sum_{k in s} (-2 wo_k) * rcp(E1[l,k]*E2[m,k] + 1)
//           (tanh via 1 trans op/cell thanks to E1*E2 = exp2(q1+q2));
//           K split 4 ways for occupancy; writes partial + transpose.
//           SW and row-constant mask terms dropped (cancel in softmax).
//  k_softmax : wave-per-row shuffle softmax, sums 4 partials + col penalty,
//           coalesced natural-layout writes (d12[b][l][m], d21t[b][m][l]).
//  k_final: out12 = tanh(P12 + d12^T-free GEMM (A already [k][m]) @ U1),
//           out21 = tanh(P21 + d21t-GEMM @ U2).

#define NEGC (-1e12f)
#define TWO_LOG2E 2.8853900817779268f
#define LOG2E 1.4426950408889634f

// ---------------------------------------------------------------- k_proj
__global__ __launch_bounds__(256) void k_proj(
    const float* __restrict__ ctx1, const float* __restrict__ ctx2,
    const float* __restrict__ Wh, const float* __restrict__ bh,
    const float* __restrict__ W12, const float* __restrict__ b12,
    const float* __restrict__ W21, const float* __restrict__ b21,
    const float* __restrict__ mask1, const float* __restrict__ mask2,
    float* __restrict__ E1, float* __restrict__ E2,
    float* __restrict__ P12, float* __restrict__ U1,
    float* __restrict__ P21, float* __restrict__ U2,
    float* __restrict__ pen1, float* __restrict__ pen2)
{
    const int t  = threadIdx.x;
    const int g  = blockIdx.z;
    const int r0 = blockIdx.x * 64;       // M in [0,1024): row = l*2+b
    const int n0 = blockIdx.y * 64;       // N in [0,256)

    const float* A; const float* W; const float* bias; int expm; float* outp;
    switch (g) {
      case 0:  A=ctx1; W=Wh;        bias=bh;   expm=1; outp=E1;  break;
      case 1:  A=ctx2; W=Wh+65536;  bias=0;    expm=1; outp=E2;  break;
      case 2:  A=ctx2; W=W12;       bias=b12;  expm=0; outp=P12; break;
      case 3:  A=ctx1; W=W12+65536; bias=0;    expm=0; outp=U1;  break;
      case 4:  A=ctx1; W=W21;       bias=b21;  expm=0; outp=P21; break;
      default: A=ctx2; W=W21+65536; bias=0;    expm=0; outp=U2;  break;
    }

    if (g == 0 && blockIdx.x == 0 && blockIdx.y == 0) {
        for (int idx = t; idx < 1024; idx += 256) {
            int row = idx >> 1, b = idx & 1;
            pen1[b * 512 + row] = (1.f - mask1[idx]) * NEGC;
            pen2[b * 512 + row] = (1.f - mask2[idx]) * NEGC;
        }
    }

    __shared__ __align__(16) float As[32 * 68];   // k-major [kk][m]
    __shared__ __align__(16) float Bs[32 * 68];   // k-major [kk][n]
    const int tm4 = (t >> 4) << 2;
    const int tn4 = (t & 15) << 2;
    float acc[4][4] = {};

    for (int k0 = 0; k0 < 256; k0 += 32) {
        #pragma unroll
        for (int i = 0; i < 2; ++i) {            // A: 64 rows x 32 k (transpose)
            int slot = i * 256 + t;
            int r = slot >> 3, kq = (slot & 7) << 2;
            float4 v = *(const float4*)(A + (r0 + r) * 256 + k0 + kq);
            As[(kq + 0) * 68 + r] = v.x;
            As[(kq + 1) * 68 + r] = v.y;
            As[(kq + 2) * 68 + r] = v.z;
            As[(kq + 3) * 68 + r] = v.w;
        }
        #pragma unroll
        for (int i = 0; i < 2; ++i) {            // B: 32 k x 64 n (straight)
            int slot = i * 256 + t;
            int bk = slot >> 4, bnq = (slot & 15) << 2;
            *(float4*)(Bs + bk * 68 + bnq) =
                *(const float4*)(W + (k0 + bk) * 256 + n0 + bnq);
        }
        __syncthreads();
        #pragma unroll 8
        for (int kk = 0; kk < 32; ++kk) {
            const float4 a = *(const float4*)(As + kk * 68 + tm4);
            const float4 b = *(const float4*)(Bs + kk * 68 + tn4);
            acc[0][0] += a.x*b.x; acc[0][1] += a.x*b.y; acc[0][2] += a.x*b.z; acc[0][3] += a.x*b.w;
            acc[1][0] += a.y*b.x; acc[1][1] += a.y*b.y; acc[1][2] += a.y*b.z; acc[1][3] += a.y*b.w;
            acc[2][0] += a.z*b.x; acc[2][1] += a.z*b.y; acc[2][2] += a.z*b.z; acc[2][3] += a.z*b.w;
            acc[3][0] += a.w*b.x; acc[3][1] += a.w*b.y; acc[3][2] += a.w*b.z; acc[3][3] += a.w*b.w;
        }
        __syncthreads();
    }

    float4 bv = make_float4(0.f, 0.f, 0.f, 0.f);
    if (bias) bv = *(const float4*)(bias + n0 + tn4);
    #pragma unroll
    for (int i = 0; i < 4; ++i) {
        int r = r0 + tm4 + i;
        int orow = ((r & 1) << 9) + (r >> 1);    // [b][l] layout
        float4 v;
        v.x = acc[i][0] + bv.x; v.y = acc[i][1] + bv.y;
        v.z = acc[i][2] + bv.z; v.w = acc[i][3] + bv.w;
        if (expm) {
            v.x = __builtin_amdgcn_exp2f(v.x * TWO_LOG2E);
            v.y = __builtin_amdgcn_exp2f(v.y * TWO_LOG2E);
            v.z = __builtin_amdgcn_exp2f(v.z * TWO_LOG2E);
            v.w = __builtin_amdgcn_exp2f(v.w * TWO_LOG2E);
        }
        *(float4*)(outp + orow * 256 + n0 + tn4) = v;
    }
}

// ---------------------------------------------------------------- k_aff
#define AFF_CELL(AV, QV, I, J) do {                                   \
    float r0_ = __builtin_amdgcn_rcpf(fmaf(AV.x, QV.x, 1.f));         \
    float r1_ = __builtin_amdgcn_rcpf(fmaf(AV.y, QV.y, 1.f));         \
    float r2_ = __builtin_amdgcn_rcpf(fmaf(AV.z, QV.z, 1.f));         \
    float r3_ = __builtin_amdgcn_rcpf(fmaf(AV.w, QV.w, 1.f));         \
    acc[I][J] = fmaf(w.x, r0_, fmaf(w.y, r1_, fmaf(w.z, r2_,          \
                fmaf(w.w, r3_, acc[I][J]))));                         \
} while (0)

__global__ __launch_bounds__(256) void k_aff(
    const float* __restrict__ E1g, const float* __restrict__ E2g,
    const float* __restrict__ wo,
    float* __restrict__ P, float* __restrict__ PT)
{
    const int t  = threadIdx.x;
    const int l0 = blockIdx.x * 64, m0 = blockIdx.y * 64;
    const int b  = blockIdx.z & 1, s = blockIdx.z >> 1;   // K-split s in [0,4)
    const int ks = s * 64;

    __shared__ __align__(16) float E1s[64 * 68];   // xor-swizzled rows
    __shared__ __align__(16) float E2s[64 * 68];
    __shared__ __align__(16) float affs[64 * 68];
    __shared__ __align__(16) float wos[64];

    if (t < 64) wos[t] = -2.f * wo[ks + t];

    #pragma unroll
    for (int i = 0; i < 4; ++i) {      // stage 64 rows x 64 k, swizzled
        int slot = i * 256 + t;
        int r = slot >> 4, kq = (slot & 15) << 2;
        int kx = kq ^ ((((r >> 2) & 7)) << 2);
        *(float4*)(E1s + r * 68 + kx) =
            *(const float4*)(E1g + (((b << 9) + l0 + r) << 8) + ks + kq);
        *(float4*)(E2s + r * 68 + kx) =
            *(const float4*)(E2g + (((b << 9) + m0 + r) << 8) + ks + kq);
    }
    __syncthreads();

    const int tl = t >> 4, tm = t & 15;
    const int lrow = tl * 272;          // (tl*4)*68
    const int mrow = tm * 272;
    const int x1 = (tl & 7) << 2;
    const int x2 = (tm & 7) << 2;
    float acc[4][4] = {};

    #pragma unroll 4
    for (int k0 = 0; k0 < 64; k0 += 4) {
        const float4 w  = *(const float4*)(wos + k0);
        const float4 a0 = *(const float4*)(E1s + lrow +       (k0 ^ x1));
        const float4 a1 = *(const float4*)(E1s + lrow + 68  + (k0 ^ x1));
        const float4 a2 = *(const float4*)(E1s + lrow + 136 + (k0 ^ x1));
        const float4 a3 = *(const float4*)(E1s + lrow + 204 + (k0 ^ x1));
        const float4 q0 = *(const float4*)(E2s + mrow +       (k0 ^ x2));
        const float4 q1 = *(const float4*)(E2s + mrow + 68  + (k0 ^ x2));
        const float4 q2 = *(const float4*)(E2s + mrow + 136 + (k0 ^ x2));
        const float4 q3 = *(const float4*)(E2s + mrow + 204 + (k0 ^ x2));
        AFF_CELL(a0, q0, 0, 0); AFF_CELL(a0, q1, 0, 1); AFF_CELL(a0, q2, 0, 2); AFF_CELL(a0, q3, 0, 3);
        AFF_CELL(a1, q0, 1, 0); AFF_CELL(a1, q1, 1, 1); AFF_CELL(a1, q2, 1, 2); AFF_CELL(a1, q3, 1, 3);
        AFF_CELL(a2, q0, 2, 0); AFF_CELL(a2, q1, 2, 1); AFF_CELL(a2, q2, 2, 2); AFF_CELL(a2, q3, 2, 3);
        AFF_CELL(a3, q0, 3, 0); AFF_CELL(a3, q1, 3, 1); AFF_CELL(a3, q2, 3, 2); AFF_CELL(a3, q3, 3, 3);
    }

    #pragma unroll
    for (int i = 0; i < 4; ++i)
        #pragma unroll
        for (int j = 0; j < 4; ++j)
            affs[(tl * 4 + i) * 68 + tm * 4 + j] = acc[i][j];
    __syncthreads();

    const int Poff = s * 524288;
    #pragma unroll
    for (int i = 0; i < 4; ++i) {
        int slot = i * 256 + t;
        int r = slot >> 4, cq = (slot & 15) << 2;
        *(float4*)(P + Poff + (((b << 9) + l0 + r) << 9) + m0 + cq) =
            *(const float4*)(affs + r * 68 + cq);
        float4 tv;
        tv.x = affs[(cq + 0) * 68 + r];
        tv.y = affs[(cq + 1) * 68 + r];
        tv.z = affs[(cq + 2) * 68 + r];
        tv.w = affs[(cq + 3) * 68 + r];
        *(float4*)(PT + Poff + (((b << 9) + m0 + r) << 9) + l0 + cq) = tv;
    }
}

// ------------------------------------------------------------- k_softmax
__global__ __launch_bounds__(256) void k_softmax(
    const float* __restrict__ P, const float* __restrict__ PT,
    const float* __restrict__ pen1, const float* __restrict__ pen2,
    float* __restrict__ d12, float* __restrict__ d21t)
{
    const int t    = threadIdx.x;
    const int rid  = blockIdx.x * 4 + (t >> 6);   // 0..2047
    const int lane = t & 63;
    const bool second = rid >= 1024;
    const int rr = rid & 1023;                    // rr = (b<<9)+x
    const int b  = rr >> 9;
    const float* base = (second ? PT : P) + rr * 512;
    const float* pen  = (second ? pen1 : pen2) + b * 512;
    float* dst = (second ? d21t : d12) + rr * 512;

    const int c = lane << 2;
    float4 v0 = *(const float4*)(base + c);
    float4 v1 = *(const float4*)(base + 256 + c);
    #pragma unroll
    for (int s = 1; s < 4; ++s) {
        float4 w0 = *(const float4*)(base + s * 524288 + c);
        float4 w1 = *(const float4*)(base + s * 524288 + 256 + c);
        v0.x += w0.x; v0.y += w0.y; v0.z += w0.z; v0.w += w0.w;
        v1.x += w1.x; v1.y += w1.y; v1.z += w1.z; v1.w += w1.w;
    }
    float4 p0 = *(const float4*)(pen + c);
    float4 p1 = *(const float4*)(pen + 256 + c);
    v0.x += p0.x; v0.y += p0.y; v0.z += p0.z; v0.w += p0.w;
    v1.x += p1.x; v1.y += p1.y; v1.z += p1.z; v1.w += p1.w;

    float mx = fmaxf(fmaxf(fmaxf(v0.x, v0.y), fmaxf(v0.z, v0.w)),
                     fmaxf(fmaxf(v1.x, v1.y), fmaxf(v1.z, v1.w)));
    #pragma unroll
    for (int off = 1; off < 64; off <<= 1)
        mx = fmaxf(mx, __shfl_xor(mx, off, 64));

    float e0 = __builtin_amdgcn_exp2f((v0.x - mx) * LOG2E);
    float e1 = __builtin_amdgcn_exp2f((v0.y - mx) * LOG2E);
    float e2 = __builtin_amdgcn_exp2f((v0.z - mx) * LOG2E);
    float e3 = __builtin_amdgcn_exp2f((v0.w - mx) * LOG2E);
    float e4 = __builtin_amdgcn_exp2f((v1.x - mx) * LOG2E);
    float e5 = __builtin_amdgcn_exp2f((v1.y - mx) * LOG2E);
    float e6 = __builtin_amdgcn_exp2f((v1.z - mx) * LOG2E);
    float e7 = __builtin_amdgcn_exp2f((v1.w - mx) * LOG2E);
    float sum = ((e0 + e1) + (e2 + e3)) + ((e4 + e5) + (e6 + e7));
    #pragma unroll
    for (int off = 1; off < 64; off <<= 1)
        sum += __shfl_xor(sum, off, 64);
    const float inv = __builtin_amdgcn_rcpf(sum);

    *(float4*)(dst + c)       = make_float4(e0 * inv, e1 * inv, e2 * inv, e3 * inv);
    *(float4*)(dst + 256 + c) = make_float4(e4 * inv, e5 * inv, e6 * inv, e7 * inv);
}

// --------------------------------------------------------------- k_final
__global__ __launch_bounds__(256) void k_final(
    const float* __restrict__ d12, const float* __restrict__ d21t,
    const float* __restrict__ U1, const float* __restrict__ U2,
    const float* __restrict__ P12, const float* __restrict__ P21,
    float* __restrict__ out)
{
    const int t   = threadIdx.x;
    const int m0  = blockIdx.x * 64, n0 = blockIdx.y * 32;
    const int dir = blockIdx.z >> 1, b = blockIdx.z & 1;
    const float* Ag = (dir == 0 ? d12 : d21t) + b * 262144;  // [k][m], stride 512
    const float* Bg = (dir == 0 ? U1  : U2)   + b * 131072;  // [k][n], stride 256
    const float* Pg = (dir == 0 ? P12 : P21)  + b * 131072;  // [m][n], stride 256
    float* o = out + (dir == 0 ? 262144 : 0);

    __shared__ __align__(16) float As[32 * 68];
    __shared__ __align__(16) float Bs[32 * 40];
    const int tm4 = (t >> 4) << 2;
    const int tn2 = (t & 15) << 1;
    float a00=0,a01=0,a10=0,a11=0,a20=0,a21=0,a30=0,a31=0;

    for (int k0 = 0; k0 < 512; k0 += 32) {
        #pragma unroll
        for (int i = 0; i < 2; ++i) {          // A: 32 k x 64 m (already [k][m])
            int slot = i * 256 + t;
            int ak = slot >> 4, amq = (slot & 15) << 2;
            *(float4*)(As + ak * 68 + amq) =
                *(const float4*)(Ag + (k0 + ak) * 512 + m0 + amq);
        }
        {
            int bk = t >> 3, bnq = (t & 7) << 2;  // B: 32 k x 32 n
            *(float4*)(Bs + bk * 40 + bnq) =
                *(const float4*)(Bg + (k0 + bk) * 256 + n0 + bnq);
        }
        __syncthreads();
        #pragma unroll 8
        for (int kk = 0; kk < 32; ++kk) {
            const float4 a  = *(const float4*)(As + kk * 68 + tm4);
            const float2 bv = *(const float2*)(Bs + kk * 40 + tn2);
            a00 += a.x*bv.x; a01 += a.x*bv.y;
            a10 += a.y*bv.x; a11 += a.y*bv.y;
            a20 += a.z*bv.x; a21 += a.z*bv.y;
            a30 += a.w*bv.x; a31 += a.w*bv.y;
        }
        __syncthreads();
    }

    float accs[4][2] = {{a00,a01},{a10,a11},{a20,a21},{a30,a31}};
    #pragma unroll
    for (int i = 0; i < 4; ++i) {
        int m = m0 + tm4 + i;
        float2 p = *(const float2*)(Pg + m * 256 + n0 + tn2);
        float vx = accs[i][0] + p.x;
        float vy = accs[i][1] + p.y;
        float tx = 1.f - 2.f * __builtin_amdgcn_rcpf(
                       __builtin_amdgcn_exp2f(vx * TWO_LOG2E) + 1.f);
        float ty = 1.f - 2.f * __builtin_amdgcn_rcpf(
                       __builtin_amdgcn_exp2f(vy * TWO_LOG2E) + 1.f);
        *(float2*)(o + (m * 2 + b) * 256 + n0 + tn2) = make_float2(tx, ty);
    }
}

// ---------------------------------------------------------------- launch
extern "C" void kernel_launch(void* const* d_in, const int* in_sizes, int n_in,
                              void* d_out, int out_size, void* d_ws, size_t ws_size,
                              hipStream_t stream)
{
    const float* ctx1 = (const float*)d_in[0];
    const float* ctx2 = (const float*)d_in[1];
    const float* m1   = (const float*)d_in[2];
    const float* m2   = (const float*)d_in[3];
    const float* Wh   = (const float*)d_in[4];
    const float* bh   = (const float*)d_in[5];
    const float* wo   = (const float*)d_in[6];
    const float* W12  = (const float*)d_in[7];
    const float* b12  = (const float*)d_in[8];
    const float* W21  = (const float*)d_in[9];
    const float* b21  = (const float*)d_in[10];
    float* out = (float*)d_out;
    float* ws  = (float*)d_ws;

    float* E1   = ws;                  // 262144
    float* E2   = E1   + 262144;       // 262144
    float* P12  = E2   + 262144;       // 262144
    float* U1   = P12  + 262144;       // 262144
    float* P21  = U1   + 262144;       // 262144
    float* U2   = P21  + 262144;       // 262144
    float* pen1 = U2   + 262144;       // 1024
    float* pen2 = pen1 + 1024;         // 1024
    float* P    = pen2 + 1024;         // 4 * 524288
    float* PT   = P    + 2097152;      // 4 * 524288
    float* d12  = PT   + 2097152;      // 524288
    float* d21t = d12  + 524288;       // 524288  (total ~27 MB)

    hipLaunchKernelGGL(k_proj, dim3(16, 4, 6), dim3(256), 0, stream,
                       ctx1, ctx2, Wh, bh, W12, b12, W21, b21, m1, m2,
                       E1, E2, P12, U1, P21, U2, pen1, pen2);
    hipLaunchKernelGGL(k_aff, dim3(8, 8, 8), dim3(256), 0, stream,
                       E1, E2, wo, P, PT);
    hipLaunchKernelGGL(k_softmax, dim3(512), dim3(256), 0, stream,
                       P, PT, pen1, pen2, d12, d21t);
    hipLaunchKernelGGL(k_final, dim3(8, 8, 4), dim3(256), 0, stream,
                       d12, d21t, U1, U2, P12, P21, out);
}